// Round 17
// baseline (24.200 us; speedup 1.0000x reference)
//
#include <hip/hip_runtime.h>
#include <math.h>

#define N_PTS   4000000
#define NQUADS  (N_PTS / 4)        // 1,000,000 quads; divisible by 64 (15625 chunks)
#define NTHREADS 256
#define NF4     (3 * NQUADS)       // 3,000,000 float4s in the stream
#define TPW     4                  // 64-quad chunks per wave
#define QPB     (NTHREADS * TPW)   // 1024 quads per block
#define NBLOCKS_P ((NQUADS + QPB - 1) / QPB)   // 977

// readfirstlane is i32-typed: bit-cast floats (r8 lesson), verified r9.
__device__ __forceinline__ float rfl_f32(float x) {
    return __int_as_float(__builtin_amdgcn_readfirstlane(__float_as_int(x)));
}

// ---------------------------------------------------------------------------
// Round 17: wave-autonomous tiles - ZERO barriers in the steady state.
// Each wave owns a private 2x3KiB LDS double buffer and processes 4 chunks of
// 64 quads: {ds_read own 48B -> prefetch next chunk -> compute -> ds_write
// own 48B -> coalesced store via cross-lane ds_read -> stage next}. All
// ordering is wave-local lgkmcnt/vmcnt (compiler-inserted); a wave never
// waits on another wave's memory drain. Per-wave VMEM width is unchanged
// (1KB/instruction) so global coalescing is identical to the block-tile
// version. 48B-stride ds_read_b128 is bank-conflict-free (12-word stride x 8
// lanes = 3x32 banks exactly). Trig per-thread (cheap) + SGPR-pinned R/T.
// Closed directions: fences (r3), float atomics (r12), int-atomic handshake
// (r15), nt-stores (r6), >48B/thread footprint (r2/r9).
// ---------------------------------------------------------------------------
__global__ __launch_bounds__(NTHREADS) void proj_kernel(
    const float4* __restrict__ pts,
    const float* __restrict__ xp, const float* __restrict__ yp,
    const float* __restrict__ zp, const float* __restrict__ rollp,
    const float* __restrict__ pitchp, const float* __restrict__ yawp,
    float4* __restrict__ vout, float* __restrict__ partials)
{
    __shared__ float4 buf[4][2][192];      // 4 waves x double 3KiB = 24.5 KiB
    __shared__ float sred[4];

    const int t = threadIdx.x;
    const int w = t >> 6;
    const int l = t & 63;

    // Every thread computes R,T (block-uniform; ~30 slots once per thread),
    // then pins to SGPRs - no LDS staging, no prologue barrier.
    const float rr = rollp[0], pp = pitchp[0], ya = yawp[0];
    const float cr = cosf(rr), sr = sinf(rr);
    const float cp = cosf(pp), sp = sinf(pp);
    const float cy = cosf(ya), sy = sinf(ya);
    const float R00 = rfl_f32(cp * cy);
    const float R01 = rfl_f32(-cp * sy);
    const float R02 = rfl_f32(sp);
    const float R10 = rfl_f32(cr * sy + sr * sp * cy);
    const float R11 = rfl_f32(cr * cy - sr * sp * sy);
    const float R12 = rfl_f32(-sr * cp);
    const float R20 = rfl_f32(sr * sy - cr * sp * cy);
    const float R21 = rfl_f32(sr * cy + cr * sp * sy);
    const float R22 = rfl_f32(cr * cp);
    const float Tx  = rfl_f32(xp[0]);
    const float Ty  = rfl_f32(yp[0]);
    const float Tz  = rfl_f32(zp[0]);

    const int wq0 = blockIdx.x * QPB + w * (TPW * 64);  // wave's first quad

    float4* __restrict__ bA = &buf[w][0][0];
    float4* __restrict__ bB = &buf[w][1][0];

    float acc = 0.0f;

    // --- prologue: stage chunk 0 into bA (wave-local, no barrier) ---
    if (wq0 < NQUADS) {
        const size_t fb = (size_t)3 * wq0;
        float4 p0 = make_float4(0.f,0.f,0.f,0.f), p1 = p0, p2 = p0;
        if (wq0 + 64 <= NQUADS) {              // full chunk (always, since 64|NQUADS)
            p0 = pts[fb + l];
            p1 = pts[fb + l + 64];
            p2 = pts[fb + l + 128];
        } else {
            if (fb + l       < NF4) p0 = pts[fb + l];
            if (fb + l + 64  < NF4) p1 = pts[fb + l + 64];
            if (fb + l + 128 < NF4) p2 = pts[fb + l + 128];
        }
        bA[l] = p0; bA[l + 64] = p1; bA[l + 128] = p2;
    }

#pragma unroll 1   // keep one iteration frame: bounded prefetch depth/VGPRs
    for (int i = 0; i < TPW; ++i) {
        const int q0 = wq0 + i * 64;
        if (q0 >= NQUADS) break;
        float4* __restrict__ cb = (i & 1) ? bB : bA;
        float4* __restrict__ nb = (i & 1) ? bA : bB;

        // Read own quad: 3x ds_read_b128, 48B stride (conflict-free).
        const float4* __restrict__ mt = (const float4*)((const float*)cb + 12 * l);
        const float4 a = mt[0];
        const float4 b = mt[1];
        const float4 c = mt[2];

        // Prefetch next chunk into registers; latency hides under compute.
        const int nq0 = q0 + 64;
        float4 n0 = make_float4(0.f,0.f,0.f,0.f), n1 = n0, n2 = n0;
        const bool havenext = (i + 1 < TPW) && (nq0 < NQUADS);
        if (havenext) {
            const size_t fb = (size_t)3 * nq0;
            if (nq0 + 64 <= NQUADS) {
                n0 = pts[fb + l];
                n1 = pts[fb + l + 64];
                n2 = pts[fb + l + 128];
            } else {
                if (fb + l       < NF4) n0 = pts[fb + l];
                if (fb + l + 64  < NF4) n1 = pts[fb + l + 64];
                if (fb + l + 128 < NF4) n2 = pts[fb + l + 128];
            }
        }

        // Compute 4 points.
        float4 o0 = make_float4(0.f,0.f,0.f,0.f), o1 = o0, o2 = o0;
        if (q0 + l < NQUADS) {
            const float px[4] = {a.x, a.w, b.z, c.y};
            const float py[4] = {a.y, b.x, b.w, c.z};
            const float pz[4] = {a.z, b.y, c.x, c.w};
            float vx[4], vy[4], vz[4];

#pragma unroll
            for (int k = 0; k < 4; ++k) {
                const float q0f = px[k] - Tx;
                const float q1f = py[k] - Ty;
                const float q2f = pz[k] - Tz;
                // v = q @ R   (v_j = sum_i q_i * R[i][j])
                const float v0 = q0f * R00 + q1f * R10 + q2f * R20;
                const float v1 = q0f * R01 + q1f * R11 + q2f * R21;
                const float v2 = q0f * R02 + q1f * R12 + q2f * R22;

                const bool dist = (v2 > 1.0f) && (v2 < 10.0f);

                // ph = v @ K^T ; ph[2] == v2
                const float ph0 = v0 * 600.0f + v2 * 640.0f;
                const float ph1 = v1 * 600.0f + v2 * 360.0f;
                const float u = ph0 / v2;        // IEEE div: mask bit-exactness
                const float wv = ph1 / v2;
                const bool fov = (v2 > 0.0f) && (u > 1.0f) && (u < 1279.0f) &&
                                 (wv > 1.0f) && (wv < 719.0f);
                const bool m = dist && fov;

                const float d  = sqrtf(v0 * v0 + v1 * v1 + v2 * v2);
                const float t2 = (d - 4.0f) * 0.5f;     // (d - MU) / SIGMA
                acc += m ? __expf(-0.5f * t2 * t2) : 0.0f;

                vx[k] = m ? v0 : 0.0f;
                vy[k] = m ? v1 : 0.0f;
                vz[k] = m ? v2 : 0.0f;
            }
            o0 = make_float4(vx[0], vy[0], vz[0], vx[1]);
            o1 = make_float4(vy[1], vz[1], vx[2], vy[2]);
            o2 = make_float4(vz[2], vx[3], vy[3], vz[3]);
        }

        // Writeback own 48B region (wave-local lgkmcnt ordering).
        float4* __restrict__ mtw = (float4*)((float*)cb + 12 * l);
        mtw[0] = o0; mtw[1] = o1; mtw[2] = o2;

        // Coalesced store: cross-lane ds_read within the wave (lockstep +
        // compiler lgkmcnt makes all lanes' writebacks visible), 1KB/instr.
        {
            const size_t fb = (size_t)3 * q0;
            if (q0 + 64 <= NQUADS) {
                vout[fb + l]       = cb[l];
                vout[fb + l + 64]  = cb[l + 64];
                vout[fb + l + 128] = cb[l + 128];
            } else {
                if (fb + l       < NF4) vout[fb + l]       = cb[l];
                if (fb + l + 64  < NF4) vout[fb + l + 64]  = cb[l + 64];
                if (fb + l + 128 < NF4) vout[fb + l + 128] = cb[l + 128];
            }
        }

        // Stage next chunk into the other buffer (vmcnt wait on prefetch;
        // WAR vs this iteration's cross-lane reads is same-wave in-order).
        if (havenext) {
            nb[l]       = n0;
            nb[l + 64]  = n1;
            nb[l + 128] = n2;
        }
    }

    // --- epilogue: per-wave reduce, ONE barrier, block partial ---
#pragma unroll
    for (int off = 32; off > 0; off >>= 1)
        acc += __shfl_down(acc, off, 64);
    if (l == 0) sred[w] = acc;
    __syncthreads();
    if (t == 0)
        partials[blockIdx.x] = sred[0] + sred[1] + sred[2] + sred[3];
}

// ---------------------------------------------------------------------------
// Loss kernel: 1024 threads, single strided pass over 977 partials, fixed
// order -> bit-identical loss per replay. Separate dispatch = the cheap
// cross-block sync (fusion closed: r3/r12/r15 all regressed).
// ---------------------------------------------------------------------------
__global__ __launch_bounds__(1024) void loss_kernel(const float* __restrict__ partials,
                                                    int n, float* __restrict__ loss_out) {
    __shared__ float sdata[16];
    float acc = 0.0f;
    for (int i = threadIdx.x; i < n; i += 1024) acc += partials[i];
#pragma unroll
    for (int off = 32; off > 0; off >>= 1)
        acc += __shfl_down(acc, off, 64);
    if ((threadIdx.x & 63) == 0) sdata[threadIdx.x >> 6] = acc;
    __syncthreads();
    if (threadIdx.x == 0) {
        float tot = 0.0f;
#pragma unroll
        for (int i = 0; i < 16; ++i) tot += sdata[i];
        loss_out[0] = 1.0f / (tot + 1e-6f);
    }
}

extern "C" void kernel_launch(void* const* d_in, const int* in_sizes, int n_in,
                              void* d_out, int out_size, void* d_ws, size_t ws_size,
                              hipStream_t stream) {
    const float4* pts  = (const float4*)d_in[0];
    const float* x     = (const float*)d_in[1];
    const float* y     = (const float*)d_in[2];
    const float* z     = (const float*)d_in[3];
    const float* roll  = (const float*)d_in[4];
    const float* pitch = (const float*)d_in[5];
    const float* yaw   = (const float*)d_in[6];

    float* out   = (float*)d_out;   // [0..12M) verts, [12M] loss
    float* parts = (float*)d_ws;    // NBLOCKS_P floats

    proj_kernel<<<NBLOCKS_P, NTHREADS, 0, stream>>>(pts, x, y, z, roll, pitch, yaw,
                                                    (float4*)out, parts);
    loss_kernel<<<1, 1024, 0, stream>>>(parts, NBLOCKS_P, out + (size_t)3 * N_PTS);
}

// Round 18
// 22.435 us; speedup vs baseline: 1.0787x; 1.0787x over previous
//
#include <hip/hip_runtime.h>
#include <math.h>

#define N_PTS   4000000
#define NQUADS  (N_PTS / 4)        // 1,000,000 quads; 1 quad = 4 pts = 12 floats
#define NTHREADS 256
#define NF4      (3 * NQUADS)      // 3,000,000 float4s in the stream
#define NTILES   ((NQUADS + NTHREADS - 1) / NTHREADS)   // 3907 tiles of 256 quads
#define TPB      4                                      // tiles per block
#define NBLOCKS_P ((NTILES + TPB - 1) / TPB)            // 977 (all co-resident)

// ---------------------------------------------------------------------------
// Round 18 = round 16 structure (verified best, 22.98us) + divide-free FOV
// mask: for v2>0, (ph0/v2 > 1) <=> (ph0 > v2), (ph0/v2 < 1279) <=>
// (ph0 < 1279*v2) — monotone, so the two IEEE div sequences (~40% of VALU)
// are replaced by two multiplies. Quotients were never output; only the
// 2^-24-wide rounding windows at the 4 boundaries could flip a mask bit
// (p ~ 3e-4 for this fixed dataset, deterministic across replays).
// Closed directions (measured negative): in-kernel fusion via fences (r3),
// float atomics (r12), int atomics (r15); nt-stores (r6); wider footprint
// (r2/r9); wave-autonomous zero-barrier tiles (r17).
// Verified structure: coalesced global IO via LDS tiles (r10), register
// prefetch (r11), dbuf + 1 barrier/tile + store-last (r13), TPB=4 (r14),
// 1024-thread loss fold (r16).
// ---------------------------------------------------------------------------
__global__ __launch_bounds__(NTHREADS) void proj_kernel(
    const float4* __restrict__ pts,
    const float* __restrict__ xp, const float* __restrict__ yp,
    const float* __restrict__ zp, const float* __restrict__ rollp,
    const float* __restrict__ pitchp, const float* __restrict__ yawp,
    float4* __restrict__ vout, float* __restrict__ partials)
{
    __shared__ float sRT[12];
    __shared__ float4 buf[2][3 * NTHREADS];    // 24 KiB double buffer
    __shared__ float sred[NTHREADS / 64];

    const int t = threadIdx.x;
    const int tbase = blockIdx.x * TPB;

    // --- prologue: issue tile0 loads; thread-0 trig overlaps load latency ---
    {
        float4 p0 = make_float4(0.f, 0.f, 0.f, 0.f), p1 = p0, p2 = p0;
        const size_t fb = (size_t)tbase * (3 * NTHREADS) + t;
        if (tbase < NTILES - 1) {              // full tile: unchecked
            p0 = pts[fb];
            p1 = pts[fb + NTHREADS];
            p2 = pts[fb + 2 * NTHREADS];
        } else {                               // partial tile
            if (fb                < NF4) p0 = pts[fb];
            if (fb +     NTHREADS < NF4) p1 = pts[fb + NTHREADS];
            if (fb + 2 * NTHREADS < NF4) p2 = pts[fb + 2 * NTHREADS];
        }

        if (t == 0) {
            const float r = rollp[0], p = pitchp[0], ya = yawp[0];
            const float cr = cosf(r),  sr = sinf(r);
            const float cp = cosf(p),  sp = sinf(p);
            const float cy = cosf(ya), sy = sinf(ya);
            // R = Rx @ Ry @ Rz, row-major
            sRT[0] = cp * cy;                 sRT[1] = -cp * sy;                sRT[2] = sp;
            sRT[3] = cr * sy + sr * sp * cy;  sRT[4] = cr * cy - sr * sp * sy;  sRT[5] = -sr * cp;
            sRT[6] = sr * sy - cr * sp * cy;  sRT[7] = sr * cy + cr * sp * sy;  sRT[8] = cr * cp;
            sRT[9] = xp[0]; sRT[10] = yp[0]; sRT[11] = zp[0];
        }
        buf[0][t]                = p0;
        buf[0][t + NTHREADS]     = p1;
        buf[0][t + 2 * NTHREADS] = p2;
    }
    __syncthreads();                                    // tile0 + sRT visible

    const float R00 = sRT[0], R01 = sRT[1], R02 = sRT[2];
    const float R10 = sRT[3], R11 = sRT[4], R12 = sRT[5];
    const float R20 = sRT[6], R21 = sRT[7], R22 = sRT[8];
    const float Tx  = sRT[9], Ty  = sRT[10], Tz = sRT[11];

    float acc = 0.0f;

#pragma unroll
    for (int i = 0; i < TPB; ++i) {
        const int tid = tbase + i;
        const int cur = i & 1;
        if (tid >= NTILES) break;

        // Read own quad (3x ds_read_b128 from own 48B region of buf[cur]).
        const float4* __restrict__ mt =
            (const float4*)((const float*)&buf[cur][0] + 12 * t);
        const float4 a = mt[0];
        const float4 b = mt[1];
        const float4 c = mt[2];

        // Issue next tile's global loads; latency hides under compute.
        float4 n0 = make_float4(0.f, 0.f, 0.f, 0.f), n1 = n0, n2 = n0;
        if (i + 1 < TPB && tid + 1 < NTILES) {
            const size_t fb = (size_t)(tid + 1) * (3 * NTHREADS) + t;
            if (tid + 1 < NTILES - 1) {        // full tile: unchecked
                n0 = pts[fb];
                n1 = pts[fb + NTHREADS];
                n2 = pts[fb + 2 * NTHREADS];
            } else {
                if (fb                < NF4) n0 = pts[fb];
                if (fb +     NTHREADS < NF4) n1 = pts[fb + NTHREADS];
                if (fb + 2 * NTHREADS < NF4) n2 = pts[fb + 2 * NTHREADS];
            }
        }

        const int q = tid * NTHREADS + t;               // global quad index
        float4 o0 = make_float4(0.f, 0.f, 0.f, 0.f), o1 = o0, o2 = o0;
        if (q < NQUADS) {
            const float px[4] = {a.x, a.w, b.z, c.y};
            const float py[4] = {a.y, b.x, b.w, c.z};
            const float pz[4] = {a.z, b.y, c.x, c.w};
            float vx[4], vy[4], vz[4];

#pragma unroll
            for (int k = 0; k < 4; ++k) {
                const float q0f = px[k] - Tx;
                const float q1f = py[k] - Ty;
                const float q2f = pz[k] - Tz;
                // v = q @ R   (v_j = sum_i q_i * R[i][j])
                const float v0 = q0f * R00 + q1f * R10 + q2f * R20;
                const float v1 = q0f * R01 + q1f * R11 + q2f * R21;
                const float v2 = q0f * R02 + q1f * R12 + q2f * R22;

                const bool dist = (v2 > 1.0f) && (v2 < 10.0f);

                // ph = v @ K^T ; ph[2] == v2. Divide-free mask: for v2>0,
                // ph0/v2 > 1 <=> ph0 > v2 ; ph0/v2 < 1279 <=> ph0 < 1279*v2.
                const float ph0 = v0 * 600.0f + v2 * 640.0f;
                const float ph1 = v1 * 600.0f + v2 * 360.0f;
                const bool fov = (v2 > 0.0f) &&
                                 (ph0 > v2) && (ph0 < 1279.0f * v2) &&
                                 (ph1 > v2) && (ph1 <  719.0f * v2);
                const bool m = dist && fov;

                const float d  = sqrtf(v0 * v0 + v1 * v1 + v2 * v2);
                const float t2 = (d - 4.0f) * 0.5f;     // (d - MU) / SIGMA
                acc += m ? __expf(-0.5f * t2 * t2) : 0.0f;

                vx[k] = m ? v0 : 0.0f;
                vy[k] = m ? v1 : 0.0f;
                vz[k] = m ? v2 : 0.0f;
            }
            o0 = make_float4(vx[0], vy[0], vz[0], vx[1]);
            o1 = make_float4(vy[1], vz[1], vx[2], vy[2]);
            o2 = make_float4(vz[2], vx[3], vy[3], vz[3]);
        }

        // Writeback to own region of buf[cur].
        float4* __restrict__ mtw = (float4*)((float*)&buf[cur][0] + 12 * t);
        mtw[0] = o0; mtw[1] = o1; mtw[2] = o2;

        // Stage next tile into the OTHER buffer (waits on prefetch loads).
        if (i + 1 < TPB && tid + 1 < NTILES) {
            buf[cur ^ 1][t]                = n0;
            buf[cur ^ 1][t + NTHREADS]     = n1;
            buf[cur ^ 1][t + 2 * NTHREADS] = n2;
        }

        __syncthreads();    // the ONE barrier: writeback + stage visible

        // Coalesced store - LAST op; its drain hides under next tile compute.
        {
            const size_t fb = (size_t)tid * (3 * NTHREADS) + t;
            if (tid < NTILES - 1) {            // full tile: unchecked
                vout[fb]                = buf[cur][t];
                vout[fb + NTHREADS]     = buf[cur][t + NTHREADS];
                vout[fb + 2 * NTHREADS] = buf[cur][t + 2 * NTHREADS];
            } else {
                if (fb                < NF4) vout[fb]                = buf[cur][t];
                if (fb +     NTHREADS < NF4) vout[fb + NTHREADS]     = buf[cur][t + NTHREADS];
                if (fb + 2 * NTHREADS < NF4) vout[fb + 2 * NTHREADS] = buf[cur][t + 2 * NTHREADS];
            }
        }
    }

    // Per-block deterministic reduction (acc=0 for invalid threads).
#pragma unroll
    for (int off = 32; off > 0; off >>= 1)
        acc += __shfl_down(acc, off, 64);
    if ((t & 63) == 0) sred[t >> 6] = acc;
    __syncthreads();
    if (t == 0) {
        float tot = 0.0f;
#pragma unroll
        for (int i = 0; i < NTHREADS / 64; ++i) tot += sred[i];
        partials[blockIdx.x] = tot;
    }
}

// ---------------------------------------------------------------------------
// Loss kernel: 1024 threads, single strided pass over 977 partials, fixed
// order -> bit-identical loss per replay. Separate dispatch = the cheap
// cross-block sync (fusion closed: r3/r12/r15 all regressed).
// ---------------------------------------------------------------------------
__global__ __launch_bounds__(1024) void loss_kernel(const float* __restrict__ partials,
                                                    int n, float* __restrict__ loss_out) {
    __shared__ float sdata[16];
    float acc = 0.0f;
    for (int i = threadIdx.x; i < n; i += 1024) acc += partials[i];
#pragma unroll
    for (int off = 32; off > 0; off >>= 1)
        acc += __shfl_down(acc, off, 64);
    if ((threadIdx.x & 63) == 0) sdata[threadIdx.x >> 6] = acc;
    __syncthreads();
    if (threadIdx.x == 0) {
        float tot = 0.0f;
#pragma unroll
        for (int i = 0; i < 16; ++i) tot += sdata[i];
        loss_out[0] = 1.0f / (tot + 1e-6f);
    }
}

extern "C" void kernel_launch(void* const* d_in, const int* in_sizes, int n_in,
                              void* d_out, int out_size, void* d_ws, size_t ws_size,
                              hipStream_t stream) {
    const float4* pts  = (const float4*)d_in[0];
    const float* x     = (const float*)d_in[1];
    const float* y     = (const float*)d_in[2];
    const float* z     = (const float*)d_in[3];
    const float* roll  = (const float*)d_in[4];
    const float* pitch = (const float*)d_in[5];
    const float* yaw   = (const float*)d_in[6];

    float* out   = (float*)d_out;   // [0..12M) verts, [12M] loss
    float* parts = (float*)d_ws;    // NBLOCKS_P floats

    proj_kernel<<<NBLOCKS_P, NTHREADS, 0, stream>>>(pts, x, y, z, roll, pitch, yaw,
                                                    (float4*)out, parts);
    loss_kernel<<<1, 1024, 0, stream>>>(parts, NBLOCKS_P, out + (size_t)3 * N_PTS);
}